// Round 1
// baseline (1163.953 us; speedup 1.0000x reference)
//
#include <hip/hip_runtime.h>
#include <math.h>

// Problem constants
#define BSZ 8
#define CIN 16
#define DD 32
#define HH 16
#define WW 16
#define LSEQ 8192
#define DIN 64
#define DSTATE 64
#define NH 16
#define HD 4
#define CONVD 192        // D_INNER + 2*D_STATE
#define DPROJ 272        // 2*64 + 2*64 + 16
#define Q 64             // chunk length
#define NC 128           // chunks per sequence
#define POOLN 256
#define PW 32             // pool window

__device__ __forceinline__ float softplusf(float x) {
    return (x > 20.f) ? x : log1pf(expf(x));
}
__device__ __forceinline__ float siluf(float x) {
    return x / (1.f + expf(-x));
}

// ---------------------------------------------------------------------------
// K1: fused in-projection + causal depthwise conv + silu.
// block = (b, tile of 64 positions). Produces z, dt(softplus), xbc(conv+silu).
// ---------------------------------------------------------------------------
__global__ __launch_bounds__(256) void k_projconv(
    const float* __restrict__ x, const float* __restrict__ Win,
    const float* __restrict__ convw, const float* __restrict__ convb,
    const float* __restrict__ dtb,
    float* __restrict__ z_buf, float* __restrict__ dt_buf, float* __restrict__ xbc,
    int dir)
{
    __shared__ float u_s[67 * 16];     // [pos][c]
    __shared__ float pre[67 * CONVD];  // pre-conv xBC, pos = l - l0 + 3
    const int tid = threadIdx.x;
    const int b = blockIdx.x >> 7;
    const int tile = blockIdx.x & 127;
    const int l0 = tile * 64;

    // stage u for 67 positions (3-halo for causal conv); u = 0 for l < 0 (conv zero-pad)
    for (int idx = tid; idx < 67 * 16; idx += 256) {
        int pos = idx % 67;
        int c = idx / 67;
        int l = l0 + pos - 3;
        float v = 0.f;
        if (l >= 0) {
            if (dir == 0) {
                v = x[(b * 16 + c) * 8192 + l];
            } else if (dir == 1) {
                int h = l >> 9, w = (l >> 5) & 15, d = l & 31;
                v = x[(((b * 16 + c) * 32 + d) * 16 + h) * 16 + w];
            } else {
                int w = l >> 9, d = (l >> 4) & 31, h = l & 15;
                v = x[(((b * 16 + c) * 32 + d) * 16 + h) * 16 + w];
            }
        }
        u_s[pos * 16 + c] = v;
    }
    __syncthreads();

    const float* Wd = Win + dir * DPROJ * 16;
    for (int idx = tid; idx < 67 * DPROJ; idx += 256) {
        int pos = idx / DPROJ;
        int p = idx % DPROJ;
        const float* w = Wd + p * 16;
        const float* u = u_s + pos * 16;
        float acc = 0.f;
        #pragma unroll
        for (int c = 0; c < 16; c++) acc += u[c] * w[c];
        int l = l0 + pos - 3;
        if (p < 64) {
            if (pos >= 3) z_buf[(b * 8192 + l) * 64 + p] = acc;
        } else if (p < 256) {
            pre[pos * CONVD + (p - 64)] = acc;
        } else {
            if (pos >= 3) {
                float xv = acc + dtb[dir * 16 + (p - 256)];
                dt_buf[(b * 8192 + l) * 16 + (p - 256)] = softplusf(xv);
            }
        }
    }
    __syncthreads();

    const float* cw = convw + dir * CONVD * 4;
    const float* cb = convb + dir * CONVD;
    for (int idx = tid; idx < 64 * CONVD; idx += 256) {
        int pm = idx / CONVD;
        int ch = idx % CONVD;
        float acc = cb[ch];
        #pragma unroll
        for (int k = 0; k < 4; k++) acc += cw[ch * 4 + k] * pre[(pm + k) * CONVD + ch];
        xbc[(b * 8192 + l0 + pm) * CONVD + ch] = siluf(acc);
    }
}

// ---------------------------------------------------------------------------
// K2: per-chunk local quantities: cumulative log-decay ct, chunk decay
// chunkA = exp(c_{Q-1}), and chunk state delta D[p][n].
// block = (b, chunk), 256 threads (thread = (p,n)).
// ---------------------------------------------------------------------------
__global__ __launch_bounds__(256) void k_chunk_local(
    const float* __restrict__ xbc, const float* __restrict__ dt_buf,
    const float* __restrict__ A_log,
    float* __restrict__ ct_buf, float* __restrict__ chunkA, float* __restrict__ Dst,
    int dir)
{
    __shared__ float Bs[64 * 64];    // [t][n]
    __shared__ float xh_s[64 * 64];  // [t][d]
    __shared__ float wbuf[16 * 64];  // [h][t]  exp(c_last - c_t) * dt_t
    __shared__ float dts[16 * 64];   // [h][t]
    const int tid = threadIdx.x;
    const int b = blockIdx.x >> 7;
    const int ck = blockIdx.x & 127;
    const int l0 = ck * 64;

    for (int idx = tid; idx < 64 * 64; idx += 256) {
        int t = idx >> 6, j = idx & 63;
        const float* row = xbc + (size_t)(b * 8192 + l0 + t) * CONVD;
        xh_s[idx] = row[j];
        Bs[idx] = row[64 + j];
    }
    for (int idx = tid; idx < 16 * 64; idx += 256) {
        int t = idx >> 4, h = idx & 15;
        dts[h * 64 + t] = dt_buf[(b * 8192 + l0 + t) * 16 + h];
    }
    __syncthreads();

    const int wave = tid >> 6;
    const int lane = tid & 63;
    for (int h = wave; h < 16; h += 4) {
        float A = -expf(A_log[dir * 16 + h]);
        float dtv = dts[h * 64 + lane];
        float v = dtv * A;
        // inclusive Hillis-Steele scan over 64 lanes
        #pragma unroll
        for (int off = 1; off < 64; off <<= 1) {
            float o = __shfl_up(v, off, 64);
            if (lane >= off) v += o;
        }
        float tot = __shfl(v, 63, 64);
        ct_buf[(b * 16 + h) * 8192 + l0 + lane] = v;
        wbuf[h * 64 + lane] = expf(tot - v) * dtv;
        if (lane == 63) chunkA[(b * 16 + h) * 128 + ck] = expf(tot);
    }
    __syncthreads();

    const int p = tid >> 6;
    const int n = tid & 63;
    for (int h = 0; h < 16; h++) {
        float acc = 0.f;
        #pragma unroll 4
        for (int t = 0; t < 64; t++) {
            acc += wbuf[h * 64 + t] * xh_s[t * 64 + h * 4 + p] * Bs[t * 64 + n];
        }
        Dst[((size_t)((b * 16 + h) * 128 + ck)) * 256 + tid] = acc;
    }
}

// ---------------------------------------------------------------------------
// K3: inter-chunk scan (sequential over 128 chunks), in place:
// Dst[k] (delta) is replaced by S_in[k] (state at chunk start).
// block = (b,h), thread = state element (p,n).
// ---------------------------------------------------------------------------
__global__ __launch_bounds__(256) void k_chunk_scan(
    float* __restrict__ Dst, const float* __restrict__ chunkA)
{
    const int bh = blockIdx.x;
    const int tid = threadIdx.x;
    float S = 0.f;
    for (int k = 0; k < NC; k++) {
        float a = chunkA[bh * 128 + k];
        float* ptr = Dst + ((size_t)(bh * 128 + k)) * 256 + tid;
        float d = *ptr;
        *ptr = S;
        S = a * S + d;
    }
}

// ---------------------------------------------------------------------------
// K4: chunk output. block = (b, chunk).
//   G[t][s] = C_t . B_s (head independent, computed once)
//   per head: y[t,p] = sum_{s<=t} G*exp(ct-cs)*dt_s*xh[s,p] + exp(ct)*(C_t . Sin[p,:])
// Writes y (pre-gate) to ybuf.
// ---------------------------------------------------------------------------
__global__ __launch_bounds__(256) void k_chunk_out(
    const float* __restrict__ xbc, const float* __restrict__ dt_buf,
    const float* __restrict__ ct_buf, const float* __restrict__ Dst,
    float* __restrict__ ybuf, int dir)
{
    __shared__ float Cs[64 * 65];    // [t][n] padded
    __shared__ float BsEw[64 * 65];  // B first, then reused as Ew per head
    __shared__ float G[64 * 65];
    __shared__ float xh_h[64 * 4];   // per-head xh [t][p]
    __shared__ float Sin_h[4 * 65];  // per-head state-in [p][n] padded
    __shared__ float ct_h[64];
    __shared__ float dt_h[64];
    const int tid = threadIdx.x;
    const int b = blockIdx.x >> 7;
    const int ck = blockIdx.x & 127;
    const int l0 = ck * 64;

    for (int idx = tid; idx < 64 * 64; idx += 256) {
        int t = idx >> 6, n = idx & 63;
        const float* row = xbc + (size_t)(b * 8192 + l0 + t) * CONVD;
        BsEw[t * 65 + n] = row[64 + n];
        Cs[t * 65 + n] = row[128 + n];
    }
    __syncthreads();

    // G = C . B^T ; thread computes 16 entries: row t = tid>>2, cols sb..sb+15
    {
        const int t = tid >> 2;
        const int sb = (tid & 3) * 16;
        #pragma unroll
        for (int i = 0; i < 16; i++) {
            int s = sb + i;
            float a = 0.f;
            #pragma unroll 8
            for (int n = 0; n < 64; n++) a += Cs[t * 65 + n] * BsEw[s * 65 + n];
            G[t * 65 + s] = a;
        }
    }
    __syncthreads();  // B no longer needed; BsEw becomes Ew

    const int t = tid >> 2;
    const int p = tid & 3;
    for (int h = 0; h < 16; h++) {
        // stage per-head data
        if (tid < 64) ct_h[tid] = ct_buf[(b * 16 + h) * 8192 + l0 + tid];
        else if (tid < 128) dt_h[tid - 64] = dt_buf[(b * 8192 + l0 + (tid - 64)) * 16 + h];
        xh_h[tid] = xbc[(size_t)(b * 8192 + l0 + (tid >> 2)) * CONVD + h * 4 + (tid & 3)];
        Sin_h[(tid >> 6) * 65 + (tid & 63)] =
            Dst[((size_t)((b * 16 + h) * 128 + ck)) * 256 + tid];
        __syncthreads();

        // Ew[t][s] = (s<=t) ? exp(ct[t]-ct[s])*dt[s] : 0
        #pragma unroll
        for (int i = 0; i < 16; i++) {
            int e = tid + 256 * i;
            int tt = e >> 6, ss = e & 63;
            float v = (ss <= tt) ? expf(ct_h[tt] - ct_h[ss]) * dt_h[ss] : 0.f;
            BsEw[tt * 65 + ss] = v;
        }
        __syncthreads();

        float acc = 0.f;
        for (int s = 0; s <= t; s++)
            acc += G[t * 65 + s] * BsEw[t * 65 + s] * xh_h[s * 4 + p];
        float inter = 0.f;
        #pragma unroll 8
        for (int n = 0; n < 64; n++) inter += Cs[t * 65 + n] * Sin_h[p * 65 + n];
        acc += expf(ct_h[t]) * inter;
        ybuf[(size_t)(b * 8192 + l0 + t) * 64 + h * 4 + p] = acc;
        __syncthreads();  // protect staged buffers before next head
    }
}

// ---------------------------------------------------------------------------
// K5: epilogue: y += Dp*xh ; gate with silu(z); RMSNorm(*norm_w); out-proj -> ys
// block = (b, tile of 64 l); thread = (t, quarter q), 16 dims each.
// ---------------------------------------------------------------------------
__global__ __launch_bounds__(256) void k_epilogue(
    const float* __restrict__ ybuf, const float* __restrict__ xbc,
    const float* __restrict__ z_buf, const float* __restrict__ Dp,
    const float* __restrict__ normw, const float* __restrict__ Wout,
    float* __restrict__ ys, int dir)
{
    __shared__ float WoutN[16 * 64];
    __shared__ float Dps[16];
    const int tid = threadIdx.x;
    for (int idx = tid; idx < 1024; idx += 256)
        WoutN[idx] = Wout[dir * 1024 + idx] * normw[dir * 64 + (idx & 63)];
    if (tid < 16) Dps[tid] = Dp[dir * 16 + tid];
    __syncthreads();

    const int b = blockIdx.x >> 7;
    const int tile = blockIdx.x & 127;
    const int t = tid >> 2;
    const int q = tid & 3;
    const int l = tile * 64 + t;
    const size_t base = (size_t)(b * 8192 + l);

    float g[16];
    float sumsq = 0.f;
    #pragma unroll
    for (int i = 0; i < 16; i++) {
        int d = q * 16 + i;
        int h = d >> 2;
        float y = ybuf[base * 64 + d];
        float xh = xbc[base * CONVD + d];
        float zv = z_buf[base * 64 + d];
        float val = (y + Dps[h] * xh) * siluf(zv);
        g[i] = val;
        sumsq += val * val;
    }
    sumsq += __shfl_xor(sumsq, 1);
    sumsq += __shfl_xor(sumsq, 2);
    float rms = rsqrtf(sumsq * (1.f / 64.f) + 1e-5f);

    float oc[16];
    #pragma unroll
    for (int c = 0; c < 16; c++) {
        float a = 0.f;
        #pragma unroll
        for (int i = 0; i < 16; i++) a += g[i] * WoutN[c * 64 + q * 16 + i];
        oc[c] = a;
    }
    #pragma unroll
    for (int c = 0; c < 16; c++) {
        oc[c] += __shfl_xor(oc[c], 1);
        oc[c] += __shfl_xor(oc[c], 2);
    }
    #pragma unroll
    for (int i = 0; i < 4; i++) {
        int c = q * 4 + i;
        ys[base * 16 + c] = oc[c] * rms;
    }
}

// ---------------------------------------------------------------------------
// K6a: BN batch stats, deterministic two-stage. 256 blocks x 256 threads,
// one row each. partials[block][0..15]=sum, [16..31]=sumsq.
// ---------------------------------------------------------------------------
__global__ __launch_bounds__(256) void k_bnstats(
    const float* __restrict__ ys, float* __restrict__ partials)
{
    const int tid = threadIdx.x;
    const int r = blockIdx.x * 256 + tid;
    float s[16], qv[16];
    const float* row = ys + (size_t)r * 16;
    #pragma unroll
    for (int c = 0; c < 16; c++) {
        float v = fmaxf(row[c], 0.f);
        s[c] = v;
        qv[c] = v * v;
    }
    #pragma unroll
    for (int off = 1; off < 64; off <<= 1) {
        #pragma unroll
        for (int c = 0; c < 16; c++) {
            s[c] += __shfl_xor(s[c], off);
            qv[c] += __shfl_xor(qv[c], off);
        }
    }
    __shared__ float red[4][32];
    const int wave = tid >> 6, lane = tid & 63;
    if (lane == 0) {
        #pragma unroll
        for (int c = 0; c < 16; c++) {
            red[wave][c] = s[c];
            red[wave][16 + c] = qv[c];
        }
    }
    __syncthreads();
    if (tid < 32) {
        float a = red[0][tid] + red[1][tid] + red[2][tid] + red[3][tid];
        partials[blockIdx.x * 32 + tid] = a;
    }
}

// K6b: final reduce + fold BN affine + linear into coefs[0..15], coefs[16]=offset
__global__ __launch_bounds__(256) void k_bnreduce(
    const float* __restrict__ partials, const float* __restrict__ gamma,
    const float* __restrict__ beta, const float* __restrict__ lin_w,
    const float* __restrict__ lin_b, float* __restrict__ coefs, int dir)
{
    __shared__ float S[32];
    __shared__ float mu_s[16], coef_s[16];
    const int tid = threadIdx.x;
    if (tid < 32) {
        float a = 0.f;
        for (int k = 0; k < 256; k++) a += partials[k * 32 + tid];
        S[tid] = a;
    }
    __syncthreads();
    if (tid < 16) {
        float mu = S[tid] * (1.f / 65536.f);
        float var = S[16 + tid] * (1.f / 65536.f) - mu * mu;
        float inv = rsqrtf(var + 1e-5f);
        float coef = inv * gamma[dir * 16 + tid] * lin_w[dir * 16 + tid];
        mu_s[tid] = mu;
        coef_s[tid] = coef;
        coefs[tid] = coef;
    }
    __syncthreads();
    if (tid == 0) {
        float off = lin_b[dir];
        for (int c = 0; c < 16; c++)
            off += beta[dir * 16 + c] * lin_w[dir * 16 + c] - mu_s[c] * coef_s[c];
        coefs[16] = off;
    }
}

// K7: fused BN-apply + linear + maxpool(32). 8 blocks x 256 threads.
__global__ __launch_bounds__(256) void k_pool(
    const float* __restrict__ ys, const float* __restrict__ coefs,
    float* __restrict__ out, int dir)
{
    const int b = blockIdx.x;
    const int j = threadIdx.x;
    const float off = coefs[16];
    float m = -3.4e38f;
    for (int i = 0; i < PW; i++) {
        int l = j * PW + i;
        const float* row = ys + (size_t)(b * 8192 + l) * 16;
        float sv = off;
        #pragma unroll
        for (int c = 0; c < 16; c++) sv += fmaxf(row[c], 0.f) * coefs[c];
        m = fmaxf(m, sv);
    }
    out[b * 768 + dir * 256 + j] = m;
}

// ---------------------------------------------------------------------------
extern "C" void kernel_launch(void* const* d_in, const int* in_sizes, int n_in,
                              void* d_out, int out_size, void* d_ws, size_t ws_size,
                              hipStream_t stream) {
    const float* x     = (const float*)d_in[0];
    const float* Win   = (const float*)d_in[1];
    const float* convw = (const float*)d_in[2];
    const float* convb = (const float*)d_in[3];
    const float* dtb   = (const float*)d_in[4];
    const float* Alog  = (const float*)d_in[5];
    const float* Dp    = (const float*)d_in[6];
    const float* normw = (const float*)d_in[7];
    const float* Wout  = (const float*)d_in[8];
    const float* gamma = (const float*)d_in[9];
    const float* beta  = (const float*)d_in[10];
    const float* linw  = (const float*)d_in[11];
    const float* linb  = (const float*)d_in[12];
    float* out = (float*)d_out;

    float* ws = (float*)d_ws;
    float* z_buf   = ws;                      // 8*8192*64   = 4,194,304
    float* dt_buf  = z_buf + 4194304;         // 8*8192*16   = 1,048,576
    float* xbc     = dt_buf + 1048576;        // 8*8192*192  = 12,582,912
    float* ct      = xbc + 12582912;          // 8*16*8192   = 1,048,576
    float* Dst     = ct + 1048576;            // 8*16*128*256= 4,194,304
    float* chA     = Dst + 4194304;           // 8*16*128    = 16,384
    float* ybuf    = chA + 16384;             // 8*8192*64   = 4,194,304
    float* ys      = ybuf + 4194304;          // 8*8192*16   = 1,048,576
    float* parts   = ys + 1048576;            // 256*32      = 8,192
    float* coefs   = parts + 8192;            // 17

    for (int dir = 0; dir < 3; ++dir) {
        k_projconv<<<dim3(1024), dim3(256), 0, stream>>>(
            x, Win, convw, convb, dtb, z_buf, dt_buf, xbc, dir);
        k_chunk_local<<<dim3(1024), dim3(256), 0, stream>>>(
            xbc, dt_buf, Alog, ct, chA, Dst, dir);
        k_chunk_scan<<<dim3(128), dim3(256), 0, stream>>>(Dst, chA);
        k_chunk_out<<<dim3(1024), dim3(256), 0, stream>>>(
            xbc, dt_buf, ct, Dst, ybuf, dir);
        k_epilogue<<<dim3(1024), dim3(256), 0, stream>>>(
            ybuf, xbc, z_buf, Dp, normw, Wout, ys, dir);
        k_bnstats<<<dim3(256), dim3(256), 0, stream>>>(ys, parts);
        k_bnreduce<<<dim3(1), dim3(256), 0, stream>>>(
            parts, gamma, beta, linw, linb, coefs, dir);
        k_pool<<<dim3(8), dim3(256), 0, stream>>>(ys, coefs, out, dir);
    }
}

// Round 2
// 625.144 us; speedup vs baseline: 1.8619x; 1.8619x over previous
//
#include <hip/hip_runtime.h>
#include <math.h>

// Problem constants
#define BSZ 8
#define CIN 16
#define LSEQ 8192
#define DIN 64
#define DSTATE 64
#define NH 16
#define HD 4
#define CONVD 192        // D_INNER + 2*D_STATE
#define DPROJ 272        // 2*64 + 2*64 + 16
#define Q 64             // chunk length
#define NC 128           // chunks per sequence
#define PW 32            // pool window
#define LOG2E 1.4426950408889634f

__device__ __forceinline__ float softplusf(float x) {
    return (x > 20.f) ? x : log1pf(expf(x));
}
__device__ __forceinline__ float siluf(float x) {
    return x / (1.f + expf(-x));
}

// DPP row_ror reduction over 16-lane rows (lanes grouped by lane>>4).
template<int CTRL>
__device__ __forceinline__ float dpp_ror_add(float x) {
    int yi = __builtin_amdgcn_update_dpp(0, __float_as_int(x), CTRL, 0xf, 0xf, false);
    return x + __int_as_float(yi);
}
__device__ __forceinline__ float rowsum16(float x) {
    x = dpp_ror_add<0x128>(x);  // row_ror:8
    x = dpp_ror_add<0x124>(x);  // row_ror:4
    x = dpp_ror_add<0x122>(x);  // row_ror:2
    x = dpp_ror_add<0x121>(x);  // row_ror:1
    return x;
}

// XOR-quad swizzle for [64][64] LDS tiles: element (row, col) stored at
// row*64 + ((col>>2 ^ row>>2)<<2 | col&3). Quad-aligned float4s stay contiguous.
#define SWZQ(row, c4) (((((c4) >> 2) ^ ((row) >> 2)) & 15) << 2)

// ---------------------------------------------------------------------------
// K1: fused in-projection + causal depthwise conv + silu. TILE=32.
// ---------------------------------------------------------------------------
__global__ __launch_bounds__(256, 4) void k_projconv(
    const float* __restrict__ x, const float* __restrict__ Win,
    const float* __restrict__ convw, const float* __restrict__ convb,
    const float* __restrict__ dtb,
    float* __restrict__ z_buf, float* __restrict__ dt_buf, float* __restrict__ xbc,
    int dir)
{
    __shared__ float u_s[35 * 16];     // [pos][c]
    __shared__ float pre[35 * CONVD];  // pre-conv xBC, pos = l - l0 + 3
    const int tid = threadIdx.x;
    const int b = blockIdx.x >> 8;
    const int tile = blockIdx.x & 255;
    const int l0 = tile * 32;

    for (int idx = tid; idx < 35 * 16; idx += 256) {
        int pos = idx % 35;
        int c = idx / 35;
        int l = l0 + pos - 3;
        float v = 0.f;
        if (l >= 0) {
            if (dir == 0) {
                v = x[(b * 16 + c) * 8192 + l];
            } else if (dir == 1) {
                int h = l >> 9, w = (l >> 5) & 15, d = l & 31;
                v = x[(((b * 16 + c) * 32 + d) * 16 + h) * 16 + w];
            } else {
                int w = l >> 9, d = (l >> 4) & 31, h = l & 15;
                v = x[(((b * 16 + c) * 32 + d) * 16 + h) * 16 + w];
            }
        }
        u_s[pos * 16 + c] = v;
    }
    __syncthreads();

    const float* Wd = Win + dir * DPROJ * 16;
    for (int idx = tid; idx < 35 * DPROJ; idx += 256) {
        int pos = idx / DPROJ;
        int p = idx % DPROJ;
        const float* w = Wd + p * 16;
        const float* u = u_s + pos * 16;
        float acc = 0.f;
        #pragma unroll
        for (int c = 0; c < 16; c++) acc += u[c] * w[c];
        int l = l0 + pos - 3;
        if (p < 64) {
            if (pos >= 3) z_buf[(b * 8192 + l) * 64 + p] = acc;
        } else if (p < 256) {
            pre[pos * CONVD + (p - 64)] = acc;
        } else {
            if (pos >= 3) {
                float xv = acc + dtb[dir * 16 + (p - 256)];
                dt_buf[(b * 8192 + l) * 16 + (p - 256)] = softplusf(xv);
            }
        }
    }
    __syncthreads();

    const float* cw = convw + dir * CONVD * 4;
    const float* cb = convb + dir * CONVD;
    for (int idx = tid; idx < 32 * CONVD; idx += 256) {
        int pm = idx / CONVD;
        int ch = idx % CONVD;
        float acc = cb[ch];
        #pragma unroll
        for (int k = 0; k < 4; k++) acc += cw[ch * 4 + k] * pre[(pm + k) * CONVD + ch];
        xbc[(b * 8192 + l0 + pm) * CONVD + ch] = siluf(acc);
    }
}

// ---------------------------------------------------------------------------
// K2: per-chunk: cumulative scaled log-decay ct2 (= ct*log2e), chunk decay
// chunkA = exp2(ct2_last), and chunk state delta D[p][n] via register-tiled matmul.
// ---------------------------------------------------------------------------
__global__ __launch_bounds__(256, 3) void k_chunk_local(
    const float* __restrict__ xbc, const float* __restrict__ dt_buf,
    const float* __restrict__ A_log,
    float* __restrict__ ct2_buf, float* __restrict__ chunkA, float* __restrict__ Dst,
    int dir)
{
    __shared__ float Bs[4096];      // [t][n]
    __shared__ float xh_s[4096];    // [t][hp] -> becomes wx after scan
    __shared__ float wbuf[16 * 66]; // [h][t]  exp2(tot2 - ct2_t) * dt_t
    __shared__ float dts[16 * 66];  // [h][t]
    const int tid = threadIdx.x;
    const int b = blockIdx.x >> 7;
    const int ck = blockIdx.x & 127;
    const int l0 = ck * 64;

    for (int i = tid; i < 1024; i += 256) {
        int r = i >> 4, c4 = (i & 15) << 2;
        const float* row = xbc + (size_t)(b * 8192 + l0 + r) * CONVD;
        *(float4*)&xh_s[r * 64 + c4] = *(const float4*)(row + c4);
        *(float4*)&Bs[r * 64 + c4] = *(const float4*)(row + 64 + c4);
    }
    for (int i = tid; i < 1024; i += 256) {
        int t = i >> 4, h = i & 15;
        dts[h * 66 + t] = dt_buf[(b * 8192 + l0 + t) * 16 + h];
    }
    __syncthreads();

    const int wave = tid >> 6;
    const int lane = tid & 63;
    for (int h = wave; h < 16; h += 4) {
        float A2 = -expf(A_log[dir * 16 + h]) * LOG2E;
        float dtv = dts[h * 66 + lane];
        float v = dtv * A2;
        #pragma unroll
        for (int off = 1; off < 64; off <<= 1) {
            float o = __shfl_up(v, off, 64);
            if (lane >= off) v += o;
        }
        float tot = __shfl(v, 63, 64);
        ct2_buf[(b * 16 + h) * 8192 + l0 + lane] = v;
        wbuf[h * 66 + lane] = exp2f(tot - v) * dtv;
        if (lane == 63) chunkA[(b * 16 + h) * 128 + ck] = exp2f(tot);
    }
    __syncthreads();

    // wx[t][hp] = wbuf[h][t] * xh[t][hp] (in place)
    for (int i = tid; i < 4096; i += 256) {
        int t = i >> 6, hp = i & 63;
        xh_s[i] *= wbuf[(hp >> 2) * 66 + t];
    }
    __syncthreads();

    // D[hp][n] = sum_t wx[t][hp] * B[t][n], register-tiled 4x4
    const int hp4 = tid >> 4;
    const int n4 = tid & 15;
    float a[4][4] = {};
    #pragma unroll 8
    for (int t = 0; t < 64; t++) {
        float4 wv = *(const float4*)&xh_s[t * 64 + 4 * hp4];
        float4 bv = *(const float4*)&Bs[t * 64 + 4 * n4];
        a[0][0] += wv.x * bv.x; a[0][1] += wv.x * bv.y; a[0][2] += wv.x * bv.z; a[0][3] += wv.x * bv.w;
        a[1][0] += wv.y * bv.x; a[1][1] += wv.y * bv.y; a[1][2] += wv.y * bv.z; a[1][3] += wv.y * bv.w;
        a[2][0] += wv.z * bv.x; a[2][1] += wv.z * bv.y; a[2][2] += wv.z * bv.z; a[2][3] += wv.z * bv.w;
        a[3][0] += wv.w * bv.x; a[3][1] += wv.w * bv.y; a[3][2] += wv.w * bv.z; a[3][3] += wv.w * bv.w;
    }
    #pragma unroll
    for (int i = 0; i < 4; i++) {
        int hp = 4 * hp4 + i;
        int h = hp >> 2, p = hp & 3;
        float4 o = make_float4(a[i][0], a[i][1], a[i][2], a[i][3]);
        *(float4*)(Dst + ((size_t)((b * 16 + h) * 128 + ck)) * 256 + p * 64 + 4 * n4) = o;
    }
}

// ---------------------------------------------------------------------------
// K3: inter-chunk scan (sequential over 128 chunks), in place, unroll-8 prefetch.
// ---------------------------------------------------------------------------
__global__ __launch_bounds__(256) void k_chunk_scan(
    float* __restrict__ Dst, const float* __restrict__ chunkA)
{
    const int bh = blockIdx.x;
    const int tid = threadIdx.x;
    float S = 0.f;
    for (int k0 = 0; k0 < NC; k0 += 8) {
        float d[8], av[8];
        #pragma unroll
        for (int j = 0; j < 8; j++) {
            d[j] = Dst[((size_t)(bh * 128 + k0 + j)) * 256 + tid];
            av[j] = chunkA[bh * 128 + k0 + j];
        }
        #pragma unroll
        for (int j = 0; j < 8; j++) {
            Dst[((size_t)(bh * 128 + k0 + j)) * 256 + tid] = S;
            S = av[j] * S + d[j];
        }
    }
}

// ---------------------------------------------------------------------------
// K4: chunk output, register-tiled. Thread = (t4 = tid>>4, x4 = tid&15).
// Fused phase: G[4t][4s] = C.B^T tile, CS[4t][4hp] = C.Sin^T tile (hp = 4*x4+q).
// Main: per head, acc over s in thread's 4 columns; DPP rowsum over 16 lanes.
// ---------------------------------------------------------------------------
__global__ __launch_bounds__(256, 3) void k_chunk_out(
    const float* __restrict__ xbc, const float* __restrict__ dt_buf,
    const float* __restrict__ ct2_buf, const float* __restrict__ Dst,
    float* __restrict__ ybuf, int dir)
{
    __shared__ float Cs[4096];      // [t][n] swizzled
    __shared__ float Bx[4096];      // B [s][n] swizzled, then xd [s][hp] swizzled
    __shared__ float Sn[4096];      // Sin [hp][n] swizzled
    __shared__ float ct2s[16 * 66]; // [h][t]
    const int tid = threadIdx.x;
    const int b = blockIdx.x >> 7;
    const int ck = blockIdx.x & 127;
    const int l0 = ck * 64;
    const int t4 = tid >> 4;
    const int x4 = tid & 15;

    // stage C, B (swizzled float4)
    for (int i = tid; i < 1024; i += 256) {
        int r = i >> 4, c4 = (i & 15) << 2;
        const float* row = xbc + (size_t)(b * 8192 + l0 + r) * CONVD;
        float4 bv = *(const float4*)(row + 64 + c4);
        float4 cv = *(const float4*)(row + 128 + c4);
        int qb = SWZQ(r, c4);
        *(float4*)&Bx[r * 64 + qb] = bv;
        *(float4*)&Cs[r * 64 + qb] = cv;
    }
    // stage Sin [hp][n]
    for (int i = tid; i < 1024; i += 256) {
        int hp = i >> 4, n4 = (i & 15) << 2;
        int h = hp >> 2, p = hp & 3;
        float4 sv = *(const float4*)(Dst + ((size_t)((b * 16 + h) * 128 + ck)) * 256 + p * 64 + n4);
        *(float4*)&Sn[hp * 64 + SWZQ(hp, n4)] = sv;
    }
    // stage ct2
    for (int i = tid; i < 1024; i += 256) {
        int h = i >> 6, t = i & 63;
        ct2s[h * 66 + t] = ct2_buf[(b * 16 + h) * 8192 + l0 + t];
    }
    __syncthreads();

    // fused G + CS register-tile phase
    float G_[4][4] = {}, CS_[4][4] = {};
    #pragma unroll 4
    for (int nt = 0; nt < 16; nt++) {
        float4 cr[4], br[4], sr[4];
        #pragma unroll
        for (int r = 0; r < 4; r++) {
            cr[r] = *(const float4*)&Cs[(4 * t4 + r) * 64 + (((nt ^ t4) & 15) << 2)];
            br[r] = *(const float4*)&Bx[(4 * x4 + r) * 64 + (((nt ^ x4) & 15) << 2)];
            sr[r] = *(const float4*)&Sn[(4 * x4 + r) * 64 + (((nt ^ x4) & 15) << 2)];
        }
        #pragma unroll
        for (int r = 0; r < 4; r++)
            #pragma unroll
            for (int q = 0; q < 4; q++) {
                G_[r][q] += cr[r].x * br[q].x + cr[r].y * br[q].y
                          + cr[r].z * br[q].z + cr[r].w * br[q].w;
                CS_[r][q] += cr[r].x * sr[q].x + cr[r].y * sr[q].y
                           + cr[r].z * sr[q].z + cr[r].w * sr[q].w;
            }
    }
    __syncthreads();  // B reads done

    // overwrite Bx with xd[s][hp] = dt[s][h]*xh[s][hp] (swizzled)
    for (int i = tid; i < 1024; i += 256) {
        int r = i >> 4, c4 = (i & 15) << 2;
        const float* row = xbc + (size_t)(b * 8192 + l0 + r) * CONVD;
        float4 xv = *(const float4*)(row + c4);
        float dtv = dt_buf[(size_t)(b * 8192 + l0 + r) * 16 + (c4 >> 2)];
        xv.x *= dtv; xv.y *= dtv; xv.z *= dtv; xv.w *= dtv;
        *(float4*)&Bx[r * 64 + SWZQ(r, c4)] = xv;
    }
    __syncthreads();

    const int tbase = 4 * t4;
    #pragma unroll 1
    for (int h = 0; h < 16; h++) {
        float ctt[4], ect[4];
        #pragma unroll
        for (int r = 0; r < 4; r++) {
            ctt[r] = ct2s[h * 66 + tbase + r];
            ect[r] = exp2f(ctt[r]);
        }
        float acc[4][4] = {};
        #pragma unroll
        for (int q = 0; q < 4; q++) {
            int s = 4 * x4 + q;
            float cs_ = ct2s[h * 66 + s];
            float4 xdv = *(const float4*)&Bx[s * 64 + (((h ^ x4) & 15) << 2)];
            #pragma unroll
            for (int r = 0; r < 4; r++) {
                float e = exp2f(ctt[r] - cs_);
                e = (s <= tbase + r) ? e : 0.f;
                float ge = G_[r][q] * e;
                acc[r][0] += ge * xdv.x; acc[r][1] += ge * xdv.y;
                acc[r][2] += ge * xdv.z; acc[r][3] += ge * xdv.w;
            }
        }
        if (x4 == h) {
            #pragma unroll
            for (int r = 0; r < 4; r++)
                #pragma unroll
                for (int p = 0; p < 4; p++)
                    acc[r][p] += ect[r] * CS_[r][p];
        }
        #pragma unroll
        for (int r = 0; r < 4; r++)
            #pragma unroll
            for (int p = 0; p < 4; p++)
                acc[r][p] = rowsum16(acc[r][p]);
        // lane x4 takes (r = x4>>2, p = x4&3)
        float out = acc[0][0];
        #pragma unroll
        for (int r = 0; r < 4; r++)
            #pragma unroll
            for (int p = 0; p < 4; p++)
                if (r || p)
                    out = (x4 == r * 4 + p) ? acc[r][p] : out;
        int rr = x4 >> 2, pp = x4 & 3;
        ybuf[(size_t)(b * 8192 + l0 + tbase + rr) * 64 + h * 4 + pp] = out;
    }
}

// ---------------------------------------------------------------------------
// K5: epilogue: y += Dp*xh ; gate silu(z); RMSNorm(*norm_w); out-proj -> ys
// ---------------------------------------------------------------------------
__global__ __launch_bounds__(256) void k_epilogue(
    const float* __restrict__ ybuf, const float* __restrict__ xbc,
    const float* __restrict__ z_buf, const float* __restrict__ Dp,
    const float* __restrict__ normw, const float* __restrict__ Wout,
    float* __restrict__ ys, int dir)
{
    __shared__ float WoutN[16 * 64];
    __shared__ float Dps[16];
    const int tid = threadIdx.x;
    for (int idx = tid; idx < 1024; idx += 256)
        WoutN[idx] = Wout[dir * 1024 + idx] * normw[dir * 64 + (idx & 63)];
    if (tid < 16) Dps[tid] = Dp[dir * 16 + tid];
    __syncthreads();

    const int b = blockIdx.x >> 7;
    const int tile = blockIdx.x & 127;
    const int t = tid >> 2;
    const int q = tid & 3;
    const int l = tile * 64 + t;
    const size_t base = (size_t)(b * 8192 + l);

    float g[16];
    float sumsq = 0.f;
    #pragma unroll
    for (int k = 0; k < 4; k++) {
        float4 y4 = *(const float4*)(ybuf + base * 64 + q * 16 + 4 * k);
        float4 x4v = *(const float4*)(xbc + base * CONVD + q * 16 + 4 * k);
        float4 z4 = *(const float4*)(z_buf + base * 64 + q * 16 + 4 * k);
        int h = (q * 16 + 4 * k) >> 2;
        float dpv = Dps[h];
        float v0 = (y4.x + dpv * x4v.x) * siluf(z4.x);
        float v1 = (y4.y + dpv * x4v.y) * siluf(z4.y);
        float v2 = (y4.z + dpv * x4v.z) * siluf(z4.z);
        float v3 = (y4.w + dpv * x4v.w) * siluf(z4.w);
        g[4 * k] = v0; g[4 * k + 1] = v1; g[4 * k + 2] = v2; g[4 * k + 3] = v3;
        sumsq += v0 * v0 + v1 * v1 + v2 * v2 + v3 * v3;
    }
    sumsq += __shfl_xor(sumsq, 1);
    sumsq += __shfl_xor(sumsq, 2);
    float rms = rsqrtf(sumsq * (1.f / 64.f) + 1e-5f);

    float oc[16];
    #pragma unroll
    for (int c = 0; c < 16; c++) {
        float a = 0.f;
        #pragma unroll
        for (int i = 0; i < 16; i++) a += g[i] * WoutN[c * 64 + q * 16 + i];
        oc[c] = a;
    }
    #pragma unroll
    for (int c = 0; c < 16; c++) {
        oc[c] += __shfl_xor(oc[c], 1);
        oc[c] += __shfl_xor(oc[c], 2);
    }
    float4 o4 = make_float4(oc[q * 4] * rms, oc[q * 4 + 1] * rms,
                            oc[q * 4 + 2] * rms, oc[q * 4 + 3] * rms);
    *(float4*)(ys + base * 16 + q * 4) = o4;
}

// ---------------------------------------------------------------------------
// K6a: BN batch stats, deterministic two-stage.
// ---------------------------------------------------------------------------
__global__ __launch_bounds__(256) void k_bnstats(
    const float* __restrict__ ys, float* __restrict__ partials)
{
    const int tid = threadIdx.x;
    const int r = blockIdx.x * 256 + tid;
    float s[16], qv[16];
    const float* row = ys + (size_t)r * 16;
    #pragma unroll
    for (int k = 0; k < 4; k++) {
        float4 v4 = *(const float4*)(row + 4 * k);
        float v0 = fmaxf(v4.x, 0.f), v1 = fmaxf(v4.y, 0.f);
        float v2 = fmaxf(v4.z, 0.f), v3 = fmaxf(v4.w, 0.f);
        s[4 * k] = v0; s[4 * k + 1] = v1; s[4 * k + 2] = v2; s[4 * k + 3] = v3;
        qv[4 * k] = v0 * v0; qv[4 * k + 1] = v1 * v1;
        qv[4 * k + 2] = v2 * v2; qv[4 * k + 3] = v3 * v3;
    }
    #pragma unroll
    for (int off = 1; off < 64; off <<= 1) {
        #pragma unroll
        for (int c = 0; c < 16; c++) {
            s[c] += __shfl_xor(s[c], off);
            qv[c] += __shfl_xor(qv[c], off);
        }
    }
    __shared__ float red[4][32];
    const int wave = tid >> 6, lane = tid & 63;
    if (lane == 0) {
        #pragma unroll
        for (int c = 0; c < 16; c++) {
            red[wave][c] = s[c];
            red[wave][16 + c] = qv[c];
        }
    }
    __syncthreads();
    if (tid < 32) {
        float a = red[0][tid] + red[1][tid] + red[2][tid] + red[3][tid];
        partials[blockIdx.x * 32 + tid] = a;
    }
}

// K6b: final reduce + fold BN affine + linear into coefs
__global__ __launch_bounds__(256) void k_bnreduce(
    const float* __restrict__ partials, const float* __restrict__ gamma,
    const float* __restrict__ beta, const float* __restrict__ lin_w,
    const float* __restrict__ lin_b, float* __restrict__ coefs, int dir)
{
    __shared__ float S[32];
    __shared__ float mu_s[16], coef_s[16];
    const int tid = threadIdx.x;
    if (tid < 32) {
        float a = 0.f;
        for (int k = 0; k < 256; k++) a += partials[k * 32 + tid];
        S[tid] = a;
    }
    __syncthreads();
    if (tid < 16) {
        float mu = S[tid] * (1.f / 65536.f);
        float var = S[16 + tid] * (1.f / 65536.f) - mu * mu;
        float inv = rsqrtf(var + 1e-5f);
        float coef = inv * gamma[dir * 16 + tid] * lin_w[dir * 16 + tid];
        mu_s[tid] = mu;
        coef_s[tid] = coef;
        coefs[tid] = coef;
    }
    __syncthreads();
    if (tid == 0) {
        float off = lin_b[dir];
        for (int c = 0; c < 16; c++)
            off += beta[dir * 16 + c] * lin_w[dir * 16 + c] - mu_s[c] * coef_s[c];
        coefs[16] = off;
    }
}

// K7: fused BN-apply + linear + maxpool(32). 64 blocks.
__global__ __launch_bounds__(256) void k_pool(
    const float* __restrict__ ys, const float* __restrict__ coefs,
    float* __restrict__ out, int dir)
{
    __shared__ float cf[17];
    const int tid = threadIdx.x;
    if (tid < 17) cf[tid] = coefs[tid];
    __syncthreads();
    const int b = blockIdx.x >> 3;
    const int jg = blockIdx.x & 7;
    const int j = jg * 32 + (tid >> 3);
    const int sub = tid & 7;
    float m = -3.4e38f;
    #pragma unroll
    for (int r = 0; r < 4; r++) {
        int l = j * PW + 8 * r + sub;
        const float* row = ys + (size_t)(b * 8192 + l) * 16;
        float sv = cf[16];
        #pragma unroll
        for (int k = 0; k < 4; k++) {
            float4 v4 = *(const float4*)(row + 4 * k);
            sv += fmaxf(v4.x, 0.f) * cf[4 * k] + fmaxf(v4.y, 0.f) * cf[4 * k + 1]
                + fmaxf(v4.z, 0.f) * cf[4 * k + 2] + fmaxf(v4.w, 0.f) * cf[4 * k + 3];
        }
        m = fmaxf(m, sv);
    }
    m = fmaxf(m, __shfl_xor(m, 1));
    m = fmaxf(m, __shfl_xor(m, 2));
    m = fmaxf(m, __shfl_xor(m, 4));
    if (sub == 0) out[b * 768 + dir * 256 + j] = m;
}

// ---------------------------------------------------------------------------
extern "C" void kernel_launch(void* const* d_in, const int* in_sizes, int n_in,
                              void* d_out, int out_size, void* d_ws, size_t ws_size,
                              hipStream_t stream) {
    const float* x     = (const float*)d_in[0];
    const float* Win   = (const float*)d_in[1];
    const float* convw = (const float*)d_in[2];
    const float* convb = (const float*)d_in[3];
    const float* dtb   = (const float*)d_in[4];
    const float* Alog  = (const float*)d_in[5];
    const float* Dp    = (const float*)d_in[6];
    const float* normw = (const float*)d_in[7];
    const float* Wout  = (const float*)d_in[8];
    const float* gamma = (const float*)d_in[9];
    const float* beta  = (const float*)d_in[10];
    const float* linw  = (const float*)d_in[11];
    const float* linb  = (const float*)d_in[12];
    float* out = (float*)d_out;

    float* ws = (float*)d_ws;
    float* z_buf   = ws;                      // 8*8192*64
    float* dt_buf  = z_buf + 4194304;         // 8*8192*16
    float* xbc     = dt_buf + 1048576;        // 8*8192*192
    float* ct2     = xbc + 12582912;          // 8*16*8192
    float* Dst     = ct2 + 1048576;           // 8*16*128*256
    float* chA     = Dst + 4194304;           // 8*16*128
    float* ybuf    = chA + 16384;             // 8*8192*64
    float* ys      = ybuf + 4194304;          // 8*8192*16
    float* parts   = ys + 1048576;            // 256*32
    float* coefs   = parts + 8192;            // 17

    for (int dir = 0; dir < 3; ++dir) {
        k_projconv<<<dim3(2048), dim3(256), 0, stream>>>(
            x, Win, convw, convb, dtb, z_buf, dt_buf, xbc, dir);
        k_chunk_local<<<dim3(1024), dim3(256), 0, stream>>>(
            xbc, dt_buf, Alog, ct2, chA, Dst, dir);
        k_chunk_scan<<<dim3(128), dim3(256), 0, stream>>>(Dst, chA);
        k_chunk_out<<<dim3(1024), dim3(256), 0, stream>>>(
            xbc, dt_buf, ct2, Dst, ybuf, dir);
        k_epilogue<<<dim3(1024), dim3(256), 0, stream>>>(
            ybuf, xbc, z_buf, Dp, normw, Wout, ys, dir);
        k_bnstats<<<dim3(256), dim3(256), 0, stream>>>(ys, parts);
        k_bnreduce<<<dim3(1), dim3(256), 0, stream>>>(
            parts, gamma, beta, linw, linb, coefs, dir);
        k_pool<<<dim3(64), dim3(256), 0, stream>>>(ys, coefs, out, dir);
    }
}